// Round 16
// baseline (1074.639 us; speedup 1.0000x reference)
//
#include <hip/hip_runtime.h>
#include <hip/hip_bf16.h>

// B=32, T=2048, D=256, H=256, CS=32, N=8, G=4H+2N=1040.
// Scan over BATCH axis (32 steps), carry (T,H). Backward dir = col-reversed W_ih.
#define B_  32
#define T_  2048
#define D_  256
#define H_  256
#define G_  1040

#define NSL 8      // e-slices of width 32 (== CS; slice s == chunk n)
#define NRB 16     // row-blocks of 128 rows
#define NMB 4      // mblocks of 32 rows (per rb)
#define NKB 32     // K16 chunks over KK=512
#define NF  5      // B col-frags: og,cg,ig,fg (32 cols) + [cols 0..15 | zeros]
#define CTRSTRIDE 64   // ints per group counter slot (256 B)

#define NBXT  512    // tiled xs blocks (B*NRB)
#define NBWSW 640    // Wsw blocks (163840/256)
#define XLP   264    // LDS x-tile row stride in elems (528 B: 16B-aligned)

using bf16   = __hip_bfloat16;
using short8 = __attribute__((ext_vector_type(8))) short;
using f32x16 = __attribute__((ext_vector_type(16))) float;
using ull    = unsigned long long;

__device__ inline float sigmoidf_(float v) {
  return __fdividef(1.f, 1.f + __expf(-v));
}
__device__ inline float tanh_(float v) {
  v = fminf(fmaxf(v, -15.f), 15.f);
  float e = __expf(2.f * v);
  return __fdividef(e - 1.f, e + 1.f);
}
__device__ inline float bf2f(unsigned short u) {
  union { unsigned int i; float f; } c; c.i = ((unsigned int)u) << 16; return c.f;
}
__device__ inline float ldF(const void* p, size_t i, int isf) {
  return isf ? ((const float*)p)[i] : bf2f(((const unsigned short*)p)[i]);
}
__device__ inline short f2bs(float v) {
  bf16 h = __float2bfloat16(v);
  return *(short*)&h;
}

// ---------------------------------------------------------------------------
// Fused prep (unchanged from R15 — both-sides-coalesced tiled xs build).
// Block 0: meta+bsum. Blocks [1,513): xs tiles. Blocks [513,1153): Wsw.
// ---------------------------------------------------------------------------
__global__ __launch_bounds__(256) void prep_all(
    const void* __restrict__ x, const int* __restrict__ sli,
    const void* __restrict__ W_ih, const void* __restrict__ b_ih,
    const void* __restrict__ W_hh, const void* __restrict__ b_hh,
    int* __restrict__ meta, float* __restrict__ bsum,
    bf16* __restrict__ xs, bf16* __restrict__ Wsw)
{
  __shared__ __align__(16) short xt[128 * XLP];   // 66 KB x tile
  const int tid = threadIdx.x;

  // ---- inline fp32 detection (all blocks; 2KB, L2-broadcast) ----
  __shared__ int s_bad;
  if (tid == 0) s_bad = 0;
  __syncthreads();
  {
    const unsigned short* xh = (const unsigned short*)x;
    int bad = 0;
    #pragma unroll
    for (int j = 0; j < 4; ++j) {
      float f = bf2f(xh[tid * 4 + j]);
      if (!(fabsf(f) < 100.f)) bad = 1;
    }
    if (bad) atomicOr(&s_bad, 1);
  }
  __syncthreads();
  const int isf = s_bad;

  const int blk = blockIdx.x;

  if (blk == 0) {
    if (tid == 0) {
      meta[0] = isf;
      bool is64 = true;
      for (int i = 1; i < 32; i += 2) if (sli[i] != 0) is64 = false;
      int base = 0;
      for (int b = 0; b < B_; ++b) {
        int v = is64 ? sli[2 * b] : sli[b];
        meta[8 + b]  = v;
        meta[40 + b] = base;
        base += v;
      }
    }
    for (int i = tid; i < G_; i += 256)
      bsum[i] = ldF(b_ih, i, isf) + ldF(b_hh, i, isf);
    return;
  }

  if (blk < 1 + NBXT) {
    const int bi = blk - 1;
    const int b  = bi >> 4;
    const int rb = bi & 15;
    const unsigned short* xh = (const unsigned short*)x;
    const float* xf = (const float*)x;

    #pragma unroll
    for (int i = 0; i < 16; ++i) {
      const int li  = i * 256 + tid;
      const int tr  = li >> 5;
      const int col = (li & 31) * 8;
      const size_t src = ((size_t)b * T_ + rb * 128 + tr) * D_ + col;
      short8 v;
      if (!isf) {
        v = *(const short8*)(xh + src);
      } else {
        #pragma unroll
        for (int j = 0; j < 8; ++j) v[j] = f2bs(xf[src + j]);
      }
      *(short8*)&xt[tr * XLP + col] = v;
    }
    __syncthreads();

    bf16* xsBase = xs + ((size_t)b * 16 + rb) * (16 * 4 * 64 * 8);
    #pragma unroll
    for (int i = 0; i < 16; ++i) {
      const int oc     = i * 256 + tid;
      const int lane_o = oc & 63;
      const int mb     = (oc >> 6) & 3;
      const int kbx    = oc >> 8;
      const int tr  = mb * 32 + (lane_o & 31);
      const int col = kbx * 16 + (lane_o >> 5) * 8;
      short8 v = *(const short8*)&xt[tr * XLP + col];
      *(short8*)(xsBase + (size_t)oc * 8) = v;
    }
    return;
  }

  {
    const int idx = (blk - 1 - NBXT) * 256 + tid;   // over 163840
    const int lane = idx & 63;
    const int f    = (idx >> 6) % NF;
    const int kb   = (idx / (64 * NF)) % NKB;
    const int sl   = (idx / (64 * NF * NKB)) % NSL;
    const int d    = idx / (64 * NF * NKB * NSL);
    const int n    = lane & 31;
    const int k0   = kb * 16 + (lane >> 5) * 8;
    const int g = (f < 4) ? (16 + f * H_ + sl * 32 + n) : ((n < 16) ? n : -1);
    short8 v;
    #pragma unroll
    for (int j = 0; j < 8; ++j) {
      float val = 0.f;
      const int k = k0 + j;
      if (g >= 0)
        val = (k < D_) ? ldF(W_ih, (size_t)g * D_ + (d ? (D_ - 1 - k) : k), isf)
                       : ldF(W_hh, (size_t)g * H_ + (k - D_), isf);
      v[j] = f2bs(val);
    }
    *(short8*)(Wsw + (size_t)idx * 8) = v;
  }
}

// ---------------------------------------------------------------------------
// Persistent fused recurrence. Round-16: OCCUPANCY DOUBLING by rb-pair merge.
//  - The per-(d,s) 128KiB W-slab forced 1 block/CU at 4 waves = 1 wave/SIMD,
//    exposing every latency. Merge the rb and rb+8 blocks of the same (d,s)
//    into ONE 512-thread 8-wave block sharing the SAME slab: 128 blocks,
//    2 waves/SIMD on busy CUs (stalls overlap; recurrence is latency-bound,
//    so idling half the CUs is the right trade). LDS 128K+20K=148K<160K;
//    VGPR 208<=256 so 2 waves/SIMD are resident.
//  - SYNC PROTOCOL SHAPE IDENTICAL to proven R13: tid0-poll -> syncthreads
//    -> reads; writes -> syncthreads -> tid0-signal. Group = (d, rbp),
//    rbp=rb&7; each of the 8 s-sibling blocks covers both rb=rbp and rbp+8
//    and signals its group counter once per step (the block barrier orders
//    both halves' h stores before the signal) -> 8 signals/step, threshold
//    8*b unchanged. Waves: w=tid>>6 in 0..7; rb = rbp + (w>>2)*8; mb = w&3.
//    All buffer layouts (xs/Wsw/hs/cs) unchanged (w -> mb in addressing).
//  - XCD swizzle: lin&7 = rbp keeps each h-exchange group on one XCD.
// ---------------------------------------------------------------------------
__global__ __launch_bounds__(512, 1) void onlstm_persist(
    const short* __restrict__ xs, const short* __restrict__ Wsw,
    short* __restrict__ hs, float* __restrict__ cs,
    const float* __restrict__ bsum, void* __restrict__ out,
    const int* __restrict__ meta, int* __restrict__ ctr,
    int b_lo, int b_hi)
{
  __shared__ short Wl[NKB * 4 * 512];              // 128 KiB: frags f0..3
  __shared__ __align__(16) short Ht[8][32][40];    // 20 KiB: per-wave hy transpose

  const int tid  = threadIdx.x;
  const int lane = tid & 63;
  const int w    = tid >> 6;            // wave 0..7
  const int mb   = w & 3;               // mblock within rb
  const int half = w >> 2;              // 0: rb=rbp, 1: rb=rbp+8

  // lin = (d*8+rbp) + 16*s  ->  lin&7 = rbp = XCD; group (d,rbp) on one XCD.
  const int lin = blockIdx.x;           // 0..127
  const int rbp = lin & 7;
  const int q   = lin >> 3;             // 0..15
  const int s   = q & 7;
  const int d   = q >> 3;
  const int rb  = rbp + half * 8;

  const int col   = lane & 31;
  const int khalf = lane >> 5;
  const int isf   = meta[0];

  const short* wsrc = Wsw + ((size_t)(d * NSL + s) * NKB) * (NF * 512);

  // ---- one-time: stage f0..3 frags into LDS (coalesced 16B/lane) ----
  for (int i = tid; i < NKB * 4 * 64; i += 512) {
    const int kb = i >> 8, rem = i & 255, f = rem >> 6, l = rem & 63;
    *(short8*)&Wl[((kb * 4 + f) << 9) + (l << 3)] =
        *(const short8*)(wsrc + ((kb * 5 + f) << 9) + (l << 3));
  }
  __syncthreads();

  // bias preloads (L1/L2 hits)
  float bg[4];
  #pragma unroll
  for (int f = 0; f < 4; ++f) bg[f] = bsum[16 + f * H_ + s * 32 + col];
  const float c0b = (col < 16) ? bsum[col] : 0.f;

  // epilogue addressing for e = s*32+col
  const int e = s * 32 + col;

  int* gctr = ctr + (size_t)(d * 8 + rbp) * CTRSTRIDE;  // 16 groups, 1 line each
  const short* w4p = wsrc + 4 * 512 + lane * 8;   // f4 frag, stride 5*512/chunk

  float* csP = cs + (((size_t)(d * NSL + s) * NRB + rb) * NMB + mb) * 1024 + lane;

  f32x16 creg;                                    // c carry: registers
  if (b_lo > 0) {
    #pragma unroll
    for (int r = 0; r < 16; ++r) creg[r] = csP[r * 64];
  } else {
    #pragma unroll
    for (int r = 0; r < 16; ++r) creg[r] = 0.f;
  }

  // prologue: synchronously prefetch step b_lo's xs chunks into registers
  short8 xn[16];
  {
    const short* aPtr = xs + (((size_t)b_lo * NRB + rb) * 16 * NMB + mb) * 512 + lane * 8;
    #pragma unroll
    for (int kb = 0; kb < 16; ++kb)
      xn[kb] = *(const short8*)(aPtr + (size_t)kb * 2048);
  }

  for (int b = b_lo; b < b_hi; ++b) {
    const int len_s  = meta[8 + b];
    const int base_s = meta[40 + b];
    const bool lastb = (b + 1 >= B_);

    f32x16 acc[NF];
    #pragma unroll
    for (int f = 0; f < NF; ++f)
      #pragma unroll
      for (int r = 0; r < 16; ++r) acc[f][r] = 0.f;

    // ---- xs half (K chunks 0..15): A from registers (cross-step prefetch
    // into the same regs); Wl frags double-buffered in regs; f4 pipelined. ----
    {
      const short* aNext = xs + (((size_t)(b + 1) * NRB + rb) * 16 * NMB + mb) * 512 + lane * 8;
      const bool pf = (b + 1 < b_hi);
      const short* w4q = w4p;
      short8 q0 = *(const short8*)(w4q);
      short8 q1 = *(const short8*)(w4q + 2560);
      short8 q2 = *(const short8*)(w4q + 5120);
      short8 wf[2][4];
      #pragma unroll
      for (int f = 0; f < 4; ++f)
        wf[0][f] = *(const short8*)&Wl[((0 * 4 + f) << 9) + (lane << 3)];
      #pragma unroll
      for (int kb = 0; kb < 16; ++kb) {
        const int cur = kb & 1;            // static after full unroll
        if (kb + 1 < 16) {
          #pragma unroll
          for (int f = 0; f < 4; ++f)
            wf[cur ^ 1][f] = *(const short8*)&Wl[(((kb + 1) * 4 + f) << 9) + (lane << 3)];
        }
        const short8 af = xn[kb];
        if (pf) xn[kb] = *(const short8*)(aNext + (size_t)kb * 2048);  // next-step prefetch
        const short8 b4 = q0;
        q0 = q1; q1 = q2;
        if (kb < 13) q2 = *(const short8*)(w4q + (kb + 3) * 2560);
        #pragma unroll
        for (int f = 0; f < 4; ++f)
          acc[f] = __builtin_amdgcn_mfma_f32_32x32x16_bf16(af, wf[cur][f], acc[f], 0, 0, 0);
        acc[4] = __builtin_amdgcn_mfma_f32_32x32x16_bf16(af, b4, acc[4], 0, 0, 0);
      }
    }

    // ---- wait: tid0 polls group (d,rbp) >= 8b, then __syncthreads
    // releases all 8 waves (proven R13 read side; barrier covers block). ----
    if (b) {
      if (tid == 0) {
        ull t0 = __builtin_amdgcn_s_memrealtime();
        while (__hip_atomic_load(gctr, __ATOMIC_RELAXED,
                                 __HIP_MEMORY_SCOPE_AGENT) < 8 * b) {
          __builtin_amdgcn_s_sleep(1);
          if (__builtin_amdgcn_s_memrealtime() - t0 > 40000000ull) break; // no hang
        }
      }
      __syncthreads();

      // prefetch all 16 h-chunks (parity (b&1)^1) via coherent 8B atomic loads
      ull hfA[16], hfB[16];
      {
        const short* hbase = hs + (((size_t)(((b & 1) ^ 1) * 2 + d) * NRB + rb) * 16 * NMB + mb) * 512;
        #pragma unroll
        for (int kb = 0; kb < 16; ++kb) {
          const ull* hp = (const ull*)(hbase + (size_t)kb * NMB * 512) + lane * 2;
          hfA[kb] = __hip_atomic_load(hp,     __ATOMIC_RELAXED, __HIP_MEMORY_SCOPE_AGENT);
          hfB[kb] = __hip_atomic_load(hp + 1, __ATOMIC_RELAXED, __HIP_MEMORY_SCOPE_AGENT);
        }
      }

      // hs half (K chunks 16..31): A from prefetched regs, Wl frags
      // double-buffered, f4 pipelined.
      const short* w4q = w4p + 16 * 2560;
      short8 q0 = *(const short8*)(w4q);
      short8 q1 = *(const short8*)(w4q + 2560);
      short8 q2 = *(const short8*)(w4q + 5120);
      short8 wf[2][4];
      #pragma unroll
      for (int f = 0; f < 4; ++f)
        wf[0][f] = *(const short8*)&Wl[(((16 * 4) + f) << 9) + (lane << 3)];
      #pragma unroll
      for (int kb = 0; kb < 16; ++kb) {
        const int cur = kb & 1;
        if (kb + 1 < 16) {
          #pragma unroll
          for (int f = 0; f < 4; ++f)
            wf[cur ^ 1][f] = *(const short8*)&Wl[(((16 + kb + 1) * 4 + f) << 9) + (lane << 3)];
        }
        union { ull u[2]; short8 v; } af;
        af.u[0] = hfA[kb]; af.u[1] = hfB[kb];
        const short8 b4 = q0;
        q0 = q1; q1 = q2;
        if (kb < 13) q2 = *(const short8*)(w4q + (kb + 3) * 2560);
        #pragma unroll
        for (int f = 0; f < 4; ++f)
          acc[f] = __builtin_amdgcn_mfma_f32_32x32x16_bf16(af.v, wf[cur][f], acc[f], 0, 0, 0);
        acc[4] = __builtin_amdgcn_mfma_f32_32x32x16_bf16(af.v, b4, acc[4], 0, 0, 0);
      }
    }
    // b==0: h is zero, hs half contributes nothing -> skipped entirely.

    // ---- epilogue ----
    // C layout: col = lane&31, row = (r&3) + 8*(r>>2) + 4*(lane>>5).
    // Stage-batched shuffle trees (16 parallel chains).
    f32x16 gv, mx, Sv, Pv;
    #pragma unroll
    for (int r = 0; r < 16; ++r) gv[r] = acc[4][r] + c0b;  // cols>=16: exactly 0
    #pragma unroll
    for (int r = 0; r < 16; ++r) mx[r] = gv[r];
    #pragma unroll
    for (int r = 0; r < 16; ++r) { float t = __shfl_xor(mx[r], 1); mx[r] = fmaxf(mx[r], t); }
    #pragma unroll
    for (int r = 0; r < 16; ++r) { float t = __shfl_xor(mx[r], 2); mx[r] = fmaxf(mx[r], t); }
    #pragma unroll
    for (int r = 0; r < 16; ++r) { float t = __shfl_xor(mx[r], 4); mx[r] = fmaxf(mx[r], t); }
    #pragma unroll
    for (int r = 0; r < 16; ++r) gv[r] = __expf(gv[r] - mx[r]);   // gv := ex
    const bool pin = (lane & 7) <= s;
    #pragma unroll
    for (int r = 0; r < 16; ++r) { Sv[r] = gv[r]; Pv[r] = pin ? gv[r] : 0.f; }
    #pragma unroll
    for (int r = 0; r < 16; ++r) { Sv[r] += __shfl_xor(Sv[r], 1); Pv[r] += __shfl_xor(Pv[r], 1); }
    #pragma unroll
    for (int r = 0; r < 16; ++r) { Sv[r] += __shfl_xor(Sv[r], 2); Pv[r] += __shfl_xor(Pv[r], 2); }
    #pragma unroll
    for (int r = 0; r < 16; ++r) { Sv[r] += __shfl_xor(Sv[r], 4); Pv[r] += __shfl_xor(Pv[r], 4); }
    #pragma unroll
    for (int r = 0; r < 16; ++r) Pv[r] = __fdividef(Pv[r], Sv[r]);  // Pv := ratio
    f32x16 cinv, cfgv;
    #pragma unroll
    for (int r = 0; r < 16; ++r) cinv[r] = 1.f - __shfl(Pv[r], khalf * 32);
    #pragma unroll
    for (int r = 0; r < 16; ++r) cfgv[r] = __shfl(Pv[r], khalf * 32 + 8);

    #pragma unroll
    for (int r = 0; r < 16; ++r) {
      const int row = (r & 3) + 8 * (r >> 2) + 4 * khalf;
      const float cin = cinv[r];
      const float cfg = cfgv[r];
      const float og = sigmoidf_(acc[0][r] + bg[0]);
      const float cg = tanh_   (acc[1][r] + bg[1]);
      const float ig = sigmoidf_(acc[2][r] + bg[2]);
      const float fg = sigmoidf_(acc[3][r] + bg[3]);
      const float ov = cfg * cin;
      const float f2 = fg * ov + (cfg - ov);
      const float i2 = ig * ov + (cin - ov);
      const float cy = f2 * creg[r] + i2 * cg;
      creg[r] = cy;
      const float hy = og * tanh_(cy);
      if (!lastb) Ht[w][row][col] = f2bs(hy);   // wave-private transpose tile
      const int t = rb * 128 + mb * 32 + row;
      if (t < len_s) {
        const size_t o = (size_t)(base_s + t) * (2 * H_) + (size_t)d * H_ + e;
        if (isf) ((float*)out)[o] = hy;
        else     ((bf16*)out)[o]  = __float2bfloat16(hy);
      }
    }

    // ---- hy -> A-frag image via coherent 8B atomic stores (4/lane);
    // skipped on the last step (never read). ----
    if (!lastb) {
      const int m  = lane & 31;
      const int k8 = lane >> 5;
      short* hbase = hs + (((size_t)((b & 1) * 2 + d) * NRB + rb) * 16 * NMB + mb) * 512;
      #pragma unroll
      for (int c = 0; c < 2; ++c) {
        ull lo = *(const ull*)&Ht[w][m][c * 16 + k8 * 8];
        ull hi = *(const ull*)&Ht[w][m][c * 16 + k8 * 8 + 4];
        ull* q2 = (ull*)(hbase + (size_t)(2 * s + c) * NMB * 512) + lane * 2;
        __hip_atomic_store(q2,     lo, __ATOMIC_RELAXED, __HIP_MEMORY_SCOPE_AGENT);
        __hip_atomic_store(q2 + 1, hi, __ATOMIC_RELAXED, __HIP_MEMORY_SCOPE_AGENT);
      }
    }

    // ---- arrive: barrier drains ALL 8 waves' stores (vmcnt(0) before
    // s_barrier), then ONE relaxed add signals the group (proven write
    // side; signal covers both rb halves). ----
    __syncthreads();
    if (tid == 0)
      __hip_atomic_fetch_add(gctr, 1, __ATOMIC_RELAXED, __HIP_MEMORY_SCOPE_AGENT);
  }

  if (b_hi < B_) {                 // per-step fallback mode: spill c carry
    #pragma unroll
    for (int r = 0; r < 16; ++r) csP[r * 64] = creg[r];
  }
}

// ---------------------------------------------------------------------------
extern "C" void kernel_launch(void* const* d_in, const int* in_sizes, int n_in,
                              void* d_out, int out_size, void* d_ws, size_t ws_size,
                              hipStream_t stream)
{
  const void* x    = d_in[0];
  const int*  sl   = (const int*)d_in[1];
  const void* W_ih = d_in[2];
  const void* b_ih = d_in[3];
  const void* W_hh = d_in[4];
  const void* b_hh = d_in[5];

  char* ws = (char*)d_ws;
  size_t off = 0;
  auto alloc = [&](size_t bytes) {
    void* p = ws + off;
    off = (off + bytes + 255) & ~(size_t)255;
    return p;
  };
  int*   meta = (int*)  alloc(128 * sizeof(int));
  short* xs   = (short*)alloc((size_t)B_ * T_ * D_ * sizeof(short));            // 32 MB
  short* Wsw  = (short*)alloc((size_t)2 * NSL * NKB * NF * 512 * sizeof(short)); // 2.6 MB
  short* hs   = (short*)alloc((size_t)2 * 2 * T_ * H_ * sizeof(short));         // 4 MB [parity][dir]
  float* bsum = (float*)alloc((size_t)G_ * sizeof(float));
  int*   ctr  = (int*)  alloc((size_t)32 * CTRSTRIDE * sizeof(int));            // padded: 1 line/group
  float* cs   = (float*)alloc((size_t)2 * NSL * NRB * NMB * 1024 * sizeof(float)); // 4 MB (fallback only)
  const bool have_cs = (off <= ws_size);

  hipMemsetAsync(ctr, 0, (size_t)32 * CTRSTRIDE * sizeof(int), stream);

  // ONE fused prep dispatch: meta+bsum, tiled xs (both-sides coalesced), Wsw.
  prep_all<<<1 + NBXT + NBWSW, 256, 0, stream>>>(
      x, sl, W_ih, b_ih, W_hh, b_hh, meta, bsum, (bf16*)xs, (bf16*)Wsw);

  // Preferred: cooperative persistent launch (co-residency guaranteed).
  // 128 blocks x 512 threads: 2 waves/SIMD on busy CUs.
  int b_lo = 0, b_hi = B_;
  void* args[] = {(void*)&xs, (void*)&Wsw, (void*)&hs, (void*)&cs, (void*)&bsum,
                  (void*)&d_out, (void*)&meta, (void*)&ctr, (void*)&b_lo, (void*)&b_hi};
  hipError_t ce = hipLaunchCooperativeKernel((const void*)onlstm_persist,
                                             dim3(128), dim3(512), args, 0, stream);
  if (ce != hipSuccess) {
    (void)hipGetLastError();   // clear error state
    if (have_cs) {
      // Fallback: per-step launches; inter-step sync = kernel boundary.
      // Counter accumulates 8/group/launch, matching the 8*b thresholds.
      for (int b = 0; b < B_; ++b)
        onlstm_persist<<<dim3(128), dim3(512), 0, stream>>>(
            xs, Wsw, hs, cs, bsum, d_out, meta, ctr, b, b + 1);
    } else {
      // Last resort: regular persistent launch (structural residency + timeout).
      onlstm_persist<<<dim3(128), dim3(512), 0, stream>>>(
          xs, Wsw, hs, cs, bsum, d_out, meta, ctr, 0, B_);
    }
  }
}